// Round 1
// baseline (26.261 us; speedup 1.0000x reference)
//
#include <hip/hip_runtime.h>

// CoarseDirectionReducer: out[b, c*8+g, h, w] = sum_j softmax(logits)[g][j] * in[b, c*24+GI[g][j], h, w]
// B=4, nc=4, NUM_FINE=24, H=W=256. Pure memory-bound channel remix (128 MB traffic).

#define NUM_FINE 24
#define NGROUP 8

__global__ __launch_bounds__(256) void coarse_reduce_kernel(
    const float4* __restrict__ in,      // (B, nc*24, H, W) viewed as float4
    const float*  __restrict__ logits,  // (8, 3)
    float4* __restrict__ out,           // (B, nc*8, H, W) viewed as float4
    int pix4,                           // H*W/4
    int total)                          // B*nc*pix4
{
    __shared__ float w[NGROUP][3];
    if (threadIdx.x < NGROUP) {
        const int g = threadIdx.x;
        float a = logits[g * 3 + 0];
        float b = logits[g * 3 + 1];
        float c = logits[g * 3 + 2];
        float m = fmaxf(a, fmaxf(b, c));
        float ea = __expf(a - m), eb = __expf(b - m), ec = __expf(c - m);
        float inv = 1.0f / (ea + eb + ec);
        w[g][0] = ea * inv;
        w[g][1] = eb * inv;
        w[g][2] = ec * inv;
    }
    __syncthreads();

    int idx = blockIdx.x * blockDim.x + threadIdx.x;
    if (idx >= total) return;

    // pix4 = 16384 = 2^14 for H=W=256
    int pix   = idx & (pix4 - 1);
    int plane = idx >> 14;              // (b*nc + c), 0..15

    const float4* ib = in  + (size_t)plane * NUM_FINE * pix4 + pix;
    float4*       ob = out + (size_t)plane * NGROUP  * pix4 + pix;

    // GROUP_IDX precomputed from the reference's GROUPS_DXDY / offset table.
    constexpr int gi[NGROUP][3] = {
        {17, 23, 18},
        {16, 21, 22},
        {15, 19, 20},
        {12, 13,  9},
        {11, 10, 14},
        { 8,  4,  3},
        { 7,  2,  1},
        { 6,  0,  5},
    };

#pragma unroll
    for (int g = 0; g < NGROUP; ++g) {
        const float w0 = w[g][0], w1 = w[g][1], w2 = w[g][2];
        const float4 x0 = ib[(size_t)gi[g][0] * pix4];
        const float4 x1 = ib[(size_t)gi[g][1] * pix4];
        const float4 x2 = ib[(size_t)gi[g][2] * pix4];
        float4 r;
        r.x = w0 * x0.x + w1 * x1.x + w2 * x2.x;
        r.y = w0 * x0.y + w1 * x1.y + w2 * x2.y;
        r.z = w0 * x0.z + w1 * x1.z + w2 * x2.z;
        r.w = w0 * x0.w + w1 * x1.w + w2 * x2.w;
        ob[(size_t)g * pix4] = r;
    }
}

extern "C" void kernel_launch(void* const* d_in, const int* in_sizes, int n_in,
                              void* d_out, int out_size, void* d_ws, size_t ws_size,
                              hipStream_t stream) {
    const float* in     = (const float*)d_in[0];  // (4, 96, 256, 256) f32
    const float* logits = (const float*)d_in[1];  // (8, 3) f32
    float* out          = (float*)d_out;          // (4, 32, 256, 256) f32

    const int pix4  = (256 * 256) / 4;            // 16384
    const int total = in_sizes[0] / (NUM_FINE * 4); // B*nc*pix4 = 262144

    const int block = 256;
    const int grid  = (total + block - 1) / block; // 1024

    coarse_reduce_kernel<<<grid, block, 0, stream>>>(
        (const float4*)in, logits, (float4*)out, pix4, total);
}

// Round 2
// 24.512 us; speedup vs baseline: 1.0714x; 1.0714x over previous
//
#include <hip/hip_runtime.h>

// CoarseDirectionReducer: out[b, c*8+g, h, w] = sum_j softmax(logits)[g][j] * in[b, c*24+GI[g][j], h, w]
// B=4, nc=4, NUM_FINE=24, H=W=256. Memory-bound channel remix: 96 MB read + 32 MB write.
//
// Layout: one block per (plane, group, chunk). Each wave = exactly 3 read
// streams + 1 write stream, contiguous 8 KB window per stream -> maximal
// DRAM stream locality. 2 float4 per thread for load ILP.

#define NUM_FINE 24
#define NGROUP 8
#define PIX4 16384        // 256*256/4
#define CHUNKS 32         // PIX4 / (256 threads * 2 float4)

__global__ __launch_bounds__(256) void coarse_reduce_kernel(
    const float4* __restrict__ in,      // (16, 24, PIX4) float4
    const float*  __restrict__ logits,  // (8, 3)
    float4* __restrict__ out)           // (16, 8, PIX4) float4
{
    // blockIdx.x = plane*(8*CHUNKS) + g*CHUNKS + chunk
    const int chunk = blockIdx.x & (CHUNKS - 1);
    const int g     = (blockIdx.x >> 5) & (NGROUP - 1);
    const int plane = blockIdx.x >> 8;

    // GROUP_IDX precomputed from the reference's GROUPS_DXDY / offset table.
    constexpr int gi[NGROUP][3] = {
        {17, 23, 18},
        {16, 21, 22},
        {15, 19, 20},
        {12, 13,  9},
        {11, 10, 14},
        { 8,  4,  3},
        { 7,  2,  1},
        { 6,  0,  5},
    };

    // Wave-uniform softmax weights for this group (compiler scalarizes).
    const float a = logits[g * 3 + 0];
    const float b = logits[g * 3 + 1];
    const float c = logits[g * 3 + 2];
    const float m  = fmaxf(a, fmaxf(b, c));
    const float ea = __expf(a - m), eb = __expf(b - m), ec = __expf(c - m);
    const float inv = 1.0f / (ea + eb + ec);
    const float w0 = ea * inv, w1 = eb * inv, w2 = ec * inv;

    const int base = chunk * 512 + threadIdx.x;  // float4 index within a channel plane

    const float4* i0 = in + (size_t)(plane * NUM_FINE + gi[g][0]) * PIX4 + base;
    const float4* i1 = in + (size_t)(plane * NUM_FINE + gi[g][1]) * PIX4 + base;
    const float4* i2 = in + (size_t)(plane * NUM_FINE + gi[g][2]) * PIX4 + base;
    float4*       ob = out + (size_t)(plane * NGROUP + g) * PIX4 + base;

#pragma unroll
    for (int k = 0; k < 2; ++k) {
        const float4 x0 = i0[k * 256];
        const float4 x1 = i1[k * 256];
        const float4 x2 = i2[k * 256];
        float4 r;
        r.x = w0 * x0.x + w1 * x1.x + w2 * x2.x;
        r.y = w0 * x0.y + w1 * x1.y + w2 * x2.y;
        r.z = w0 * x0.z + w1 * x1.z + w2 * x2.z;
        r.w = w0 * x0.w + w1 * x1.w + w2 * x2.w;
        ob[k * 256] = r;
    }
}

extern "C" void kernel_launch(void* const* d_in, const int* in_sizes, int n_in,
                              void* d_out, int out_size, void* d_ws, size_t ws_size,
                              hipStream_t stream) {
    const float* in     = (const float*)d_in[0];  // (4, 96, 256, 256) f32
    const float* logits = (const float*)d_in[1];  // (8, 3) f32
    float* out          = (float*)d_out;          // (4, 32, 256, 256) f32

    const int grid = 16 * NGROUP * CHUNKS;        // 4096 blocks
    coarse_reduce_kernel<<<grid, 256, 0, stream>>>(
        (const float4*)in, logits, (float4*)out);
}